// Round 4
// baseline (125.968 us; speedup 1.0000x reference)
//
#include <hip/hip_runtime.h>
#include <hip/hip_bf16.h>

#define MARGIN  0.2f
#define NEG_INF -1e30f
#define POS_INF 1e30f

#define B_SZ 8192
#define D_SZ 128
#define CS   32      // col splits (256 cols each)
#define RBS  32      // row blocks (256 rows each)

typedef __bf16 bf16x8 __attribute__((ext_vector_type(8)));
typedef float  f32x4  __attribute__((ext_vector_type(4)));

// ---------------- Kernel 1: fp32 -> bf16 convert (8 elems/thread) ----------------
__global__ __launch_bounds__(256) void k_convert(const float* __restrict__ in,
                                                 __bf16* __restrict__ out) {
    int i = (blockIdx.x * 256 + threadIdx.x) * 8;
    float4 v0 = *reinterpret_cast<const float4*>(in + i);
    float4 v1 = *reinterpret_cast<const float4*>(in + i + 4);
    bf16x8 o;
    o[0] = (__bf16)v0.x; o[1] = (__bf16)v0.y; o[2] = (__bf16)v0.z; o[3] = (__bf16)v0.w;
    o[4] = (__bf16)v1.x; o[5] = (__bf16)v1.y; o[6] = (__bf16)v1.z; o[7] = (__bf16)v1.w;
    *reinterpret_cast<bf16x8*>(out + i) = o;
}

// ---------------- Kernel 2: fused GEMM + hard mining ----------------
// grid (32 rb, 32 cs). Block = 256 thr = 4 waves. Block tile: 256 rows x 256 cols.
// Wave w owns rows [rb*256 + w*64, +64); all 4 waves iterate the SAME 16 col-tiles
// (L1 reuse of B fragments). B loads double-buffered, fully unrolled.
__global__ __launch_bounds__(256) void k_mine(const __bf16* __restrict__ imb,
                                              const int* __restrict__ ids,
                                              float* __restrict__ wsmax,
                                              float* __restrict__ wsmin) {
    const int rb   = blockIdx.x;
    const int cs   = blockIdx.y;
    const int w    = threadIdx.x >> 6;
    const int lane = threadIdx.x & 63;
    const int quad = lane >> 4;          // 0..3 -> K-chunk
    const int lr   = lane & 15;          // 0..15 -> row (A) / col (B)

    const int rowbase = rb * 256 + w * 64;
    const int col0    = cs * 256;

    // A fragments: 4 strips x 4 K-frags (row = lr, k = kf*32 + quad*8 + j)
    bf16x8 afrag[4][4];
    #pragma unroll
    for (int s = 0; s < 4; ++s) {
        const __bf16* p = imb + (size_t)(rowbase + s * 16 + lr) * D_SZ + quad * 8;
        #pragma unroll
        for (int kf = 0; kf < 4; ++kf)
            afrag[s][kf] = *reinterpret_cast<const bf16x8*>(p + kf * 32);
    }

    // per-lane row ids (C layout: row = quad*4 + r within strip)
    int   rid[4][4];
    float mxn[4][4], mnp[4][4];
    #pragma unroll
    for (int s = 0; s < 4; ++s)
        #pragma unroll
        for (int r = 0; r < 4; ++r) {
            rid[s][r] = ids[rowbase + s * 16 + quad * 4 + r];
            mxn[s][r] = NEG_INF;
            mnp[s][r] = POS_INF;
        }

    const __bf16* bbase = imb + (size_t)col0 * D_SZ;

    // double-buffered B fragments + col ids
    bf16x8 bbuf[2][4];
    int    cidb[2];
    {
        const __bf16* q = bbase + (size_t)lr * D_SZ + quad * 8;
        #pragma unroll
        for (int kf = 0; kf < 4; ++kf)
            bbuf[0][kf] = *reinterpret_cast<const bf16x8*>(q + kf * 32);
        cidb[0] = ids[col0 + lr];
    }

    #pragma unroll
    for (int t = 0; t < 16; ++t) {
        if (t + 1 < 16) {   // prefetch next tile (compile-time resolved)
            const __bf16* q = bbase + (size_t)((t + 1) * 16 + lr) * D_SZ + quad * 8;
            #pragma unroll
            for (int kf = 0; kf < 4; ++kf)
                bbuf[(t + 1) & 1][kf] = *reinterpret_cast<const bf16x8*>(q + kf * 32);
            cidb[(t + 1) & 1] = ids[col0 + (t + 1) * 16 + lr];
        }
        const int cid = cidb[t & 1];
        #pragma unroll
        for (int s = 0; s < 4; ++s) {
            f32x4 acc = {0.f, 0.f, 0.f, 0.f};
            #pragma unroll
            for (int kf = 0; kf < 4; ++kf)
                acc = __builtin_amdgcn_mfma_f32_16x16x32_bf16(afrag[s][kf], bbuf[t & 1][kf], acc, 0, 0, 0);
            // 5-op masking: diag check dropped (raw diag = ||v||^2 >= 0, folded
            // away by min(0,.) in k_final, matching the reference's zeroed diag)
            #pragma unroll
            for (int r = 0; r < 4; ++r) {
                float sv   = acc[r];
                bool  same = (rid[s][r] == cid);
                mxn[s][r] = fmaxf(mxn[s][r], same ? NEG_INF : sv);
                mnp[s][r] = fminf(mnp[s][r], same ? sv : POS_INF);
            }
        }
    }

    // epilogue: 16-lane butterfly (lanes sharing a row), write partials [row][cs]
    #pragma unroll
    for (int s = 0; s < 4; ++s)
        #pragma unroll
        for (int r = 0; r < 4; ++r) {
            float mx = mxn[s][r];
            float mn = mnp[s][r];
            #pragma unroll
            for (int m = 1; m < 16; m <<= 1) {
                mx = fmaxf(mx, __shfl_xor(mx, m, 64));
                mn = fminf(mn, __shfl_xor(mn, m, 64));
            }
            if (lr == 0) {
                int row = rowbase + s * 16 + quad * 4 + r;
                wsmax[(size_t)row * CS + cs] = mx;
                wsmin[(size_t)row * CS + cs] = mn;
            }
        }
}

// ---------------- Kernel 3: final reduce ----------------
__global__ __launch_bounds__(256) void k_final(const float* __restrict__ wsmax,
                                               const float* __restrict__ wsmin,
                                               float* __restrict__ out) {
    int r = blockIdx.x * 256 + threadIdx.x;
    float mx = NEG_INF;
    float mn = 0.0f;   // zeroed diagonal is always a positive candidate
    #pragma unroll
    for (int c = 0; c < CS; c += 4) {
        f32x4 vx = *reinterpret_cast<const f32x4*>(wsmax + (size_t)r * CS + c);
        f32x4 vn = *reinterpret_cast<const f32x4*>(wsmin + (size_t)r * CS + c);
        mx = fmaxf(mx, fmaxf(fmaxf(vx[0], vx[1]), fmaxf(vx[2], vx[3])));
        mn = fminf(mn, fminf(fminf(vn[0], vn[1]), fminf(vn[2], vn[3])));
    }
    float cost = fmaxf(MARGIN + mx - mn, 0.0f);
    #pragma unroll
    for (int m = 1; m < 64; m <<= 1)
        cost += __shfl_xor(cost, m, 64);
    __shared__ float part[4];
    if ((threadIdx.x & 63) == 0) part[threadIdx.x >> 6] = cost;
    __syncthreads();
    if (threadIdx.x == 0)
        atomicAdd(out, part[0] + part[1] + part[2] + part[3]);
}

extern "C" void kernel_launch(void* const* d_in, const int* in_sizes, int n_in,
                              void* d_out, int out_size, void* d_ws, size_t ws_size,
                              hipStream_t stream) {
    const float* im  = (const float*)d_in[0];
    const int*   ids = (const int*)d_in[1];
    float*       out = (float*)d_out;

    __bf16* imb   = (__bf16*)d_ws;                                    // 2 MB
    float*  wsmax = (float*)((char*)d_ws + (size_t)B_SZ * D_SZ * 2);  // 1 MB
    float*  wsmin = wsmax + (size_t)B_SZ * CS;                        // 1 MB

    hipMemsetAsync(d_out, 0, sizeof(float), stream);

    k_convert<<<(B_SZ * D_SZ) / (256 * 8), 256, 0, stream>>>(im, imb);
    k_mine<<<dim3(RBS, CS), 256, 0, stream>>>(imb, ids, wsmax, wsmin);
    k_final<<<B_SZ / 256, 256, 0, stream>>>(wsmax, wsmin, out);
}

// Round 6
// 100.444 us; speedup vs baseline: 1.2541x; 1.2541x over previous
//
#include <hip/hip_runtime.h>
#include <hip/hip_bf16.h>

#define MARGIN  0.2f
#define NEG_INF -1e30f
#define POS_INF 1e30f

#define B_SZ 8192
#define D_SZ 128
#define CS   16                      // col splits (512 cols each)
#define BLK_COLS 512
#define PHASE_COLS 64
#define NPH (BLK_COLS / PHASE_COLS)  // 8

typedef __bf16 bf16x8 __attribute__((ext_vector_type(8)));
typedef __bf16 bf16x4 __attribute__((ext_vector_type(4)));
typedef float  f32x4  __attribute__((ext_vector_type(4)));

// ---------------- Kernel 1: fp32 -> bf16 convert ----------------
__global__ __launch_bounds__(256) void k_convert(const float* __restrict__ in,
                                                 __bf16* __restrict__ out) {
    int i = (blockIdx.x * 256 + threadIdx.x) * 4;
    float4 v = *reinterpret_cast<const float4*>(in + i);
    bf16x4 o;
    o[0] = (__bf16)v.x; o[1] = (__bf16)v.y; o[2] = (__bf16)v.z; o[3] = (__bf16)v.w;
    *reinterpret_cast<bf16x4*>(out + i) = o;
}

// ---------------- Kernel 2: fused GEMM + hard mining ----------------
// 512 blocks (32 rb x 16 cs via XCD-contiguous swizzle), 256 thr = 4 waves.
// Wave owns 64 rows; A-frags live in registers (64 VGPR). B-panel staged to
// LDS with global_load_lds in kf-chunked fragment order: chunk(tile,kf) is
// 1KB, lane l holds B[col0+tile*16+(l&15)][kf*32+(l>>4)*8 ..+8] -- both DMA
// write (uniform base + lane*16) and ds_read_b128 (base + lane*16) linear,
// conflict-free. 2-phase pipeline: stage(p+1) issued before compute(p),
// single vmcnt(0)+s_barrier per phase (T3 minimum pattern).
__global__ __launch_bounds__(256, 3) void k_mine(const __bf16* __restrict__ imb,
                                                 const int* __restrict__ ids,
                                                 float* __restrict__ wsmax,
                                                 float* __restrict__ wsmin) {
    __shared__ __bf16 bpanel[2][PHASE_COLS * D_SZ];   // 2 x 16KB
    __shared__ int    ids_s[BLK_COLS];                // 2KB

    const int bid = blockIdx.x;
    const int wg  = (bid & 7) * 64 + (bid >> 3);   // bijective XCD swizzle (512%8==0)
    const int rb  = wg & 31;
    const int cs  = wg >> 5;

    const int tid  = threadIdx.x;
    const int w    = tid >> 6;
    const int lane = tid & 63;
    const int quad = lane >> 4;
    const int lr   = lane & 15;

    const int rowbase = rb * 256 + w * 64;
    const int col0    = cs * BLK_COLS;

    // A fragments: 4 strips x 4 kf (row = lr, k = kf*32 + quad*8 + j)
    bf16x8 afrag[4][4];
    #pragma unroll
    for (int s = 0; s < 4; ++s) {
        const __bf16* p = imb + (size_t)(rowbase + s * 16 + lr) * D_SZ + quad * 8;
        #pragma unroll
        for (int kf = 0; kf < 4; ++kf)
            afrag[s][kf] = *reinterpret_cast<const bf16x8*>(p + kf * 32);
    }

    // row ids (C layout: row = quad*4 + r within strip)
    int rid[4][4];
    #pragma unroll
    for (int s = 0; s < 4; ++s)
        #pragma unroll
        for (int r = 0; r < 4; ++r)
            rid[s][r] = ids[rowbase + s * 16 + quad * 4 + r];

    // col ids -> LDS (compiler inserts the vmcnt for myids automatically)
    int2 myids = *reinterpret_cast<const int2*>(ids + col0 + tid * 2);
    *reinterpret_cast<int2*>(&ids_s[tid * 2]) = myids;

    // stage phase 0: wave w stages tile w (4 chunks)
    {
        const __bf16* src = imb + (size_t)(col0 + w * 16 + lr) * D_SZ + quad * 8;
        #pragma unroll
        for (int kf = 0; kf < 4; ++kf)
            __builtin_amdgcn_global_load_lds(
                (const __attribute__((address_space(1))) unsigned int*)(src + kf * 32),
                (__attribute__((address_space(3))) unsigned int*)(&bpanel[0][(w * 4 + kf) * 512]),
                16, 0, 0);
    }
    asm volatile("s_waitcnt vmcnt(0) lgkmcnt(0)" ::: "memory");
    __builtin_amdgcn_s_barrier();

    float mxn[4][4], mnp[4][4];
    #pragma unroll
    for (int s = 0; s < 4; ++s)
        #pragma unroll
        for (int r = 0; r < 4; ++r) { mxn[s][r] = NEG_INF; mnp[s][r] = POS_INF; }

    #pragma unroll 1
    for (int p = 0; p < NPH; ++p) {
        if (p + 1 < NPH) {   // prefetch next phase into other buffer
            const int nbuf = (p + 1) & 1;
            const __bf16* src = imb + (size_t)(col0 + (p + 1) * PHASE_COLS + w * 16 + lr) * D_SZ + quad * 8;
            #pragma unroll
            for (int kf = 0; kf < 4; ++kf)
                __builtin_amdgcn_global_load_lds(
                    (const __attribute__((address_space(1))) unsigned int*)(src + kf * 32),
                    (__attribute__((address_space(3))) unsigned int*)(&bpanel[nbuf][(w * 4 + kf) * 512]),
                    16, 0, 0);
        }
        const int buf = p & 1;
        #pragma unroll 1
        for (int tt = 0; tt < 4; ++tt) {
            const int cid = ids_s[p * PHASE_COLS + tt * 16 + lr];
            bf16x8 bfr[4];
            const __bf16* bp = &bpanel[buf][tt * 4 * 512] + lane * 8;
            #pragma unroll
            for (int kf = 0; kf < 4; ++kf)
                bfr[kf] = *reinterpret_cast<const bf16x8*>(bp + kf * 512);
            #pragma unroll
            for (int s = 0; s < 4; ++s) {
                f32x4 acc = {0.f, 0.f, 0.f, 0.f};
                #pragma unroll
                for (int kf = 0; kf < 4; ++kf)
                    acc = __builtin_amdgcn_mfma_f32_16x16x32_bf16(afrag[s][kf], bfr[kf], acc, 0, 0, 0);
                // diag dropped: raw diag = ||v||^2 >= 0, absorbed by min(0,.) in k_final
                #pragma unroll
                for (int r = 0; r < 4; ++r) {
                    float sv   = acc[r];
                    bool  same = (rid[s][r] == cid);
                    mxn[s][r] = fmaxf(mxn[s][r], same ? NEG_INF : sv);
                    mnp[s][r] = fminf(mnp[s][r], same ? sv : POS_INF);
                }
            }
        }
        asm volatile("s_waitcnt vmcnt(0) lgkmcnt(0)" ::: "memory");
        __builtin_amdgcn_s_barrier();
    }

    // epilogue: 16-lane butterfly over lr, write partials [row][CS]
    #pragma unroll
    for (int s = 0; s < 4; ++s)
        #pragma unroll
        for (int r = 0; r < 4; ++r) {
            float mx = mxn[s][r];
            float mn = mnp[s][r];
            #pragma unroll
            for (int m = 1; m < 16; m <<= 1) {
                mx = fmaxf(mx, __shfl_xor(mx, m, 64));
                mn = fminf(mn, __shfl_xor(mn, m, 64));
            }
            if (lr == 0) {
                int row = rowbase + s * 16 + quad * 4 + r;
                wsmax[(size_t)row * CS + cs] = mx;
                wsmin[(size_t)row * CS + cs] = mn;
            }
        }
}

// ---------------- Kernel 3: final reduce ----------------
__global__ __launch_bounds__(256) void k_final(const float* __restrict__ wsmax,
                                               const float* __restrict__ wsmin,
                                               float* __restrict__ out) {
    int r = blockIdx.x * 256 + threadIdx.x;
    float mx = NEG_INF;
    float mn = 0.0f;   // zeroed diagonal is always a positive candidate
    #pragma unroll
    for (int c = 0; c < CS; c += 4) {
        f32x4 vx = *reinterpret_cast<const f32x4*>(wsmax + (size_t)r * CS + c);
        f32x4 vn = *reinterpret_cast<const f32x4*>(wsmin + (size_t)r * CS + c);
        mx = fmaxf(mx, fmaxf(fmaxf(vx[0], vx[1]), fmaxf(vx[2], vx[3])));
        mn = fminf(mn, fminf(fminf(vn[0], vn[1]), fminf(vn[2], vn[3])));
    }
    float cost = fmaxf(MARGIN + mx - mn, 0.0f);
    #pragma unroll
    for (int m = 1; m < 64; m <<= 1)
        cost += __shfl_xor(cost, m, 64);
    __shared__ float part[4];
    if ((threadIdx.x & 63) == 0) part[threadIdx.x >> 6] = cost;
    __syncthreads();
    if (threadIdx.x == 0)
        atomicAdd(out, part[0] + part[1] + part[2] + part[3]);
}

extern "C" void kernel_launch(void* const* d_in, const int* in_sizes, int n_in,
                              void* d_out, int out_size, void* d_ws, size_t ws_size,
                              hipStream_t stream) {
    const float* im  = (const float*)d_in[0];
    const int*   ids = (const int*)d_in[1];
    float*       out = (float*)d_out;

    __bf16* imb   = (__bf16*)d_ws;                                    // 2 MB
    float*  wsmax = (float*)((char*)d_ws + (size_t)B_SZ * D_SZ * 2);  // 512 KB
    float*  wsmin = wsmax + (size_t)B_SZ * CS;                        // 512 KB

    hipMemsetAsync(d_out, 0, sizeof(float), stream);

    k_convert<<<(B_SZ * D_SZ) / (256 * 4), 256, 0, stream>>>(im, imb);
    k_mine<<<32 * CS, 256, 0, stream>>>(imb, ids, wsmax, wsmin);
    k_final<<<B_SZ / 256, 256, 0, stream>>>(wsmax, wsmin, out);
}

// Round 7
// 98.604 us; speedup vs baseline: 1.2775x; 1.0187x over previous
//
#include <hip/hip_runtime.h>
#include <hip/hip_bf16.h>

#define MARGIN  0.2f
#define NEG_INF -1e30f
#define POS_INF 1e30f

#define B_SZ 8192
#define D_SZ 128
#define CS   16                      // col splits (512 cols each)
#define BLK_COLS 512
#define PHASE_COLS 64
#define NPH (BLK_COLS / PHASE_COLS)  // 8

typedef __bf16 bf16x8 __attribute__((ext_vector_type(8)));
typedef float  f32x4  __attribute__((ext_vector_type(4)));
typedef float  f32x16 __attribute__((ext_vector_type(16)));

// ---------------- Kernel 1: fp32 -> bf16 convert (8 elems/thread) ----------------
__global__ __launch_bounds__(256) void k_convert(const float* __restrict__ in,
                                                 __bf16* __restrict__ out) {
    int i = (blockIdx.x * 256 + threadIdx.x) * 8;
    float4 v0 = *reinterpret_cast<const float4*>(in + i);
    float4 v1 = *reinterpret_cast<const float4*>(in + i + 4);
    bf16x8 o;
    o[0] = (__bf16)v0.x; o[1] = (__bf16)v0.y; o[2] = (__bf16)v0.z; o[3] = (__bf16)v0.w;
    o[4] = (__bf16)v1.x; o[5] = (__bf16)v1.y; o[6] = (__bf16)v1.z; o[7] = (__bf16)v1.w;
    *reinterpret_cast<bf16x8*>(out + i) = o;
}

// ---------------- Kernel 2: fused GEMM + hard mining (32x32x16 MFMA) ----------------
// 1024 blocks = 64 rb (128 rows) x 16 cs (512 cols), XCD-contiguous swizzle.
// Block = 256 thr = 4 waves; wave w owns rows [rb*128 + w*32, +32).
// B-panel per 64-col phase staged to LDS via global_load_lds in chunked
// fragment order: chunk(tile,kf) = 1KB, lane l holds
// B[tile*32+(l&31)][kf*16+(l>>5)*8 ..+8] -- DMA write (uniform base + lane*16B)
// and ds_read_b128 (base + lane*16B) both linear, conflict-free.
// 2-phase pipeline: stage(p+1) issued before compute(p), single vmcnt(0)+
// s_barrier per phase.
__global__ __launch_bounds__(256, 3) void k_mine(const __bf16* __restrict__ imb,
                                                 const int* __restrict__ ids,
                                                 float* __restrict__ wsmax,
                                                 float* __restrict__ wsmin) {
    __shared__ __bf16 bpanel[2][PHASE_COLS * D_SZ];   // 2 x 16KB
    __shared__ int    ids_s[BLK_COLS];                // 2KB

    const int bid = blockIdx.x;
    const int wg  = (bid & 7) * 128 + (bid >> 3);   // bijective (1024%8==0)
    const int rb  = wg & 63;
    const int cs  = wg >> 6;                        // 2 cs values per XCD

    const int tid  = threadIdx.x;
    const int w    = tid >> 6;
    const int lane = tid & 63;
    const int half = lane >> 5;      // 0/1 -> K sub-chunk
    const int l5   = lane & 31;      // row (A) / col (B)

    const int rowbase = rb * 128 + w * 32;
    const int col0    = cs * BLK_COLS;

    // staging role of this wave: chunks c = w*4+j ; tile = w>>1, kf0 = (w&1)*4
    const int s_tile = w >> 1;
    const int s_kf0  = (w & 1) * 4;

    // ---- prologue: issue stage(0) first so it overlaps reg loads ----
    {
        const __bf16* src = imb + (size_t)(col0 + s_tile * 32 + l5) * D_SZ + s_kf0 * 16 + half * 8;
        #pragma unroll
        for (int j = 0; j < 4; ++j)
            __builtin_amdgcn_global_load_lds(
                (const __attribute__((address_space(1))) unsigned int*)(src + j * 16),
                (__attribute__((address_space(3))) unsigned int*)(&bpanel[0][(s_tile * 8 + s_kf0 + j) * 512]),
                16, 0, 0);
    }

    // A fragments: 8 kf chunks (row = l5, k = kf*16 + half*8 + j)
    bf16x8 afrag[8];
    {
        const __bf16* p = imb + (size_t)(rowbase + l5) * D_SZ + half * 8;
        #pragma unroll
        for (int kf = 0; kf < 8; ++kf)
            afrag[kf] = *reinterpret_cast<const bf16x8*>(p + kf * 16);
    }

    // row ids for C layout: row = (r&3) + 8*(r>>2) + 4*half
    int rid[16];
    #pragma unroll
    for (int r = 0; r < 16; ++r)
        rid[r] = ids[rowbase + (r & 3) + 8 * (r >> 2) + 4 * half];

    // col ids -> LDS
    *reinterpret_cast<int2*>(&ids_s[tid * 2]) =
        *reinterpret_cast<const int2*>(ids + col0 + tid * 2);

    asm volatile("s_waitcnt vmcnt(0) lgkmcnt(0)" ::: "memory");
    __builtin_amdgcn_s_barrier();

    float mxn[16], mnp[16];
    #pragma unroll
    for (int r = 0; r < 16; ++r) { mxn[r] = NEG_INF; mnp[r] = POS_INF; }

    #pragma unroll 1
    for (int p = 0; p < NPH; ++p) {
        if (p + 1 < NPH) {   // prefetch next phase into other buffer
            const int nbuf = (p + 1) & 1;
            const __bf16* src = imb + (size_t)(col0 + (p + 1) * PHASE_COLS + s_tile * 32 + l5) * D_SZ
                                + s_kf0 * 16 + half * 8;
            #pragma unroll
            for (int j = 0; j < 4; ++j)
                __builtin_amdgcn_global_load_lds(
                    (const __attribute__((address_space(1))) unsigned int*)(src + j * 16),
                    (__attribute__((address_space(3))) unsigned int*)(&bpanel[nbuf][(s_tile * 8 + s_kf0 + j) * 512]),
                    16, 0, 0);
        }
        const int buf = p & 1;
        #pragma unroll
        for (int t = 0; t < 2; ++t) {
            const __bf16* bbase = &bpanel[buf][t * 4096] + (size_t)lane * 8;
            f32x16 acc = {};
            #pragma unroll
            for (int kf = 0; kf < 8; ++kf) {
                bf16x8 bfr = *reinterpret_cast<const bf16x8*>(bbase + kf * 512);
                acc = __builtin_amdgcn_mfma_f32_32x32x16_bf16(afrag[kf], bfr, acc, 0, 0, 0);
            }
            const int cid = ids_s[p * PHASE_COLS + t * 32 + l5];
            // diag dropped: raw diag = ||v||^2 >= 0, absorbed by min(0,.) in k_final
            #pragma unroll
            for (int r = 0; r < 16; ++r) {
                float sv   = acc[r];
                bool  same = (rid[r] == cid);
                mxn[r] = fmaxf(mxn[r], same ? NEG_INF : sv);
                mnp[r] = fminf(mnp[r], same ? sv : POS_INF);
            }
        }
        asm volatile("s_waitcnt vmcnt(0) lgkmcnt(0)" ::: "memory");
        __builtin_amdgcn_s_barrier();
    }

    // epilogue: butterfly over the 32 lanes sharing each row set (masks<32
    // never cross the half boundary), writers at l5==0
    #pragma unroll
    for (int r = 0; r < 16; ++r) {
        float mx = mxn[r];
        float mn = mnp[r];
        #pragma unroll
        for (int m = 1; m < 32; m <<= 1) {
            mx = fmaxf(mx, __shfl_xor(mx, m, 64));
            mn = fminf(mn, __shfl_xor(mn, m, 64));
        }
        if (l5 == 0) {
            int row = rowbase + (r & 3) + 8 * (r >> 2) + 4 * half;
            wsmax[(size_t)row * CS + cs] = mx;
            wsmin[(size_t)row * CS + cs] = mn;
        }
    }
}

// ---------------- Kernel 3: final reduce ----------------
__global__ __launch_bounds__(128) void k_final(const float* __restrict__ wsmax,
                                               const float* __restrict__ wsmin,
                                               float* __restrict__ out) {
    int r = blockIdx.x * 128 + threadIdx.x;
    float mx = NEG_INF;
    float mn = 0.0f;   // zeroed diagonal is always a positive candidate
    #pragma unroll
    for (int c = 0; c < CS; c += 4) {
        f32x4 vx = *reinterpret_cast<const f32x4*>(wsmax + (size_t)r * CS + c);
        f32x4 vn = *reinterpret_cast<const f32x4*>(wsmin + (size_t)r * CS + c);
        mx = fmaxf(mx, fmaxf(fmaxf(vx[0], vx[1]), fmaxf(vx[2], vx[3])));
        mn = fminf(mn, fminf(fminf(vn[0], vn[1]), fminf(vn[2], vn[3])));
    }
    float cost = fmaxf(MARGIN + mx - mn, 0.0f);
    #pragma unroll
    for (int m = 1; m < 64; m <<= 1)
        cost += __shfl_xor(cost, m, 64);
    __shared__ float part[2];
    if ((threadIdx.x & 63) == 0) part[threadIdx.x >> 6] = cost;
    __syncthreads();
    if (threadIdx.x == 0)
        atomicAdd(out, part[0] + part[1]);
}

extern "C" void kernel_launch(void* const* d_in, const int* in_sizes, int n_in,
                              void* d_out, int out_size, void* d_ws, size_t ws_size,
                              hipStream_t stream) {
    const float* im  = (const float*)d_in[0];
    const int*   ids = (const int*)d_in[1];
    float*       out = (float*)d_out;

    __bf16* imb   = (__bf16*)d_ws;                                    // 2 MB
    float*  wsmax = (float*)((char*)d_ws + (size_t)B_SZ * D_SZ * 2);  // 512 KB
    float*  wsmin = wsmax + (size_t)B_SZ * CS;                        // 512 KB

    hipMemsetAsync(d_out, 0, sizeof(float), stream);

    k_convert<<<(B_SZ * D_SZ) / (256 * 8), 256, 0, stream>>>(im, imb);
    k_mine<<<64 * CS, 256, 0, stream>>>(imb, ids, wsmax, wsmin);
    k_final<<<B_SZ / 128, 128, 0, stream>>>(wsmax, wsmin, out);
}